// Round 13
// baseline (766.978 us; speedup 1.0000x reference)
//
#include <hip/hip_runtime.h>

#define B_IMG 8
#define D_DIM 32
#define NPIX 262144          // 512*512
#define K_CL 16
#define CHUNK 1024
#define CHUNKS (NPIX / CHUNK)    // 256
#define F4_D (NPIX / 4)          // f4 stride between channels
#define AST 264                  // acc row stride (256 + 8 pad)

typedef float f4 __attribute__((ext_vector_type(4)));

__device__ __forceinline__ float wave_sum(float v) {
#pragma unroll
  for (int off = 32; off > 0; off >>= 1) v += __shfl_xor(v, off, 64);
  return v;
}

// Parallel flush: 16 threads/row, each sums 16 floats (4x b128), 4-shuffle
// reduce within the 16-lane group, lane c==0 atomically adds; then zero.
__device__ __forceinline__ void flushP(float (*acc)[AST], int tid,
                                       float* target, int stride) {
  const int r = tid >> 4, c = tid & 15;
  const f4* src = (const f4*)&acc[r][c << 4];
  f4 s0 = src[0], s1 = src[1], s2 = src[2], s3 = src[3];
  float t = (s0[0] + s0[1] + s0[2] + s0[3]) + (s1[0] + s1[1] + s1[2] + s1[3]) +
            (s2[0] + s2[1] + s2[2] + s2[3]) + (s3[0] + s3[1] + s3[2] + s3[3]);
  t += __shfl_xor(t, 1, 64);
  t += __shfl_xor(t, 2, 64);
  t += __shfl_xor(t, 4, 64);
  t += __shfl_xor(t, 8, 64);
  if (c == 0) unsafeAtomicAdd(&target[r * stride], t);
  f4* dst = (f4*)&acc[r][c << 4];
  dst[0] = (f4)0.f; dst[1] = (f4)0.f; dst[2] = (f4)0.f; dst[3] = (f4)0.f;
}

// ---------------- Pass A: counts + per-(k,d) sums ----------------
__global__ __launch_bounds__(256, 8) void k_sums(const float* __restrict__ emb,
                                                 const int* __restrict__ gt,
                                                 float* __restrict__ sums,
                                                 float* __restrict__ counts) {
  __shared__ float acc[K_CL][AST];          // 16.9 KB -> 8+ blocks/CU
  const int tid = threadIdx.x;
  const int b = blockIdx.x >> 8;            // CHUNKS == 256
  const int chunk = blockIdx.x & (CHUNKS - 1);
  const int base = chunk * CHUNK;

  // zero acc (1056 f4)
#pragma unroll
  for (int i = 0; i < 5; i++) {
    const int idx = tid + (i << 8);
    if (idx < (K_CL * AST) / 4) ((f4*)acc)[idx] = (f4)0.f;
  }

  int lb[4];
  {
    const int4 a = ((const int4*)(gt + (size_t)b * NPIX + base))[tid];
    lb[0] = a.x; lb[1] = a.y; lb[2] = a.z; lb[3] = a.w;
  }
  __syncthreads();

  // counts round: distinct column per thread -> collision-free ds_add
#pragma unroll
  for (int j = 0; j < 4; j++) atomicAdd(&acc[lb[j]][tid], 1.0f);
  __syncthreads();
  flushP(acc, tid, counts + b * K_CL, 1);
  __syncthreads();

  const f4* P = (const f4*)(emb + (size_t)b * D_DIM * NPIX + base);
  for (int d = 0; d < D_DIM; d++) {
    const f4 v = P[(size_t)d * F4_D + tid];
#pragma unroll
    for (int j = 0; j < 4; j++) atomicAdd(&acc[lb[j]][tid], v[j]);
    __syncthreads();
    flushP(acc, tid, sums + (size_t)b * K_CL * D_DIM + d, D_DIM);
    __syncthreads();
  }
}

// ---------------- k_means: means, msq, distance+reg loss (8 blocks) ----------------
__global__ __launch_bounds__(256) void k_means(const float* __restrict__ sums,
                                               const float* __restrict__ counts,
                                               float* __restrict__ mt,       // [b][d][k]
                                               float* __restrict__ msq_g,    // [b][k]
                                               float* __restrict__ dist_reg) {
  __shared__ float mm[K_CL][33];
  __shared__ float msq_s[K_CL];
  __shared__ float red4[4];
  const int b = blockIdx.x;
  const int t = threadIdx.x;

#pragma unroll
  for (int e0 = 0; e0 < 2; e0++) {
    const int e = t + (e0 << 8);            // e = k*32 + d
    const int k = e >> 5, d = e & 31;
    const float c = fmaxf(counts[b * K_CL + k], 1.0f);
    const float m = sums[(size_t)b * K_CL * D_DIM + e] / c;
    mm[k][d] = m;
    mt[(size_t)b * D_DIM * K_CL + d * K_CL + k] = m;   // transposed for k_var
  }
  __syncthreads();
  if (t < K_CL) {
    float s = 0.f;
#pragma unroll
    for (int d = 0; d < D_DIM; d++) { const float m = mm[t][d]; s = fmaf(m, m, s); }
    msq_s[t] = s;
    msq_g[b * K_CL + t] = s;
  }
  __syncthreads();

  const int i = t >> 4, j = t & 15;
  float sq = 0.f;
#pragma unroll
  for (int d = 0; d < D_DIM; d++) {
    const float df = mm[i][d] - mm[j][d];
    sq = fmaf(df, df, sq);
  }
  float contrib = 0.f;
  if (i < j) {
    const float h = fmaxf(3.0f - sqrtf(sq), 0.0f);     // 2*DIST_THETA
    contrib = h * h;
  }
  const float tot = wave_sum(contrib);
  if ((t & 63) == 0) red4[t >> 6] = tot;
  __syncthreads();
  if (t == 0) {
    const float dist = (red4[0] + red4[1] + red4[2] + red4[3]) * (1.0f / 240.0f);
    float reg = 0.f;
#pragma unroll
    for (int k = 0; k < K_CL; k++) reg += sqrtf(msq_s[k]);
    dist_reg[b] = dist + 0.001f * (reg * (1.0f / 16.0f));
  }
}

// ---------------- Pass C: variance loss, 4-deep pipelined ----------------
__global__ __launch_bounds__(256, 8) void k_var(const float* __restrict__ emb,
                                                const int* __restrict__ gt,
                                                const float* __restrict__ mt,
                                                const float* __restrict__ msq_g,
                                                float* __restrict__ var_sums) {
  __shared__ float tm[D_DIM][K_CL];         // 2*mean, [d][k]
  __shared__ float msq[K_CL];
  __shared__ float vacc[K_CL][16];
  const int tid = threadIdx.x;
  const int b = blockIdx.x >> 8;            // CHUNKS == 256
  const int chunk = blockIdx.x & (CHUNKS - 1);
  const int base = chunk * CHUNK;
  const int col = tid & 15;

#pragma unroll
  for (int e0 = 0; e0 < 2; e0++) {
    const int e = tid + (e0 << 8);
    ((float*)tm)[e] = 2.0f * mt[(size_t)b * D_DIM * K_CL + e];
  }
  if (tid < K_CL) msq[tid] = msq_g[b * K_CL + tid];
  ((float*)vacc)[tid] = 0.f;

  int lb[4];
  {
    const int4 a = ((const int4*)(gt + (size_t)b * NPIX + base))[tid];
    lb[0] = a.x; lb[1] = a.y; lb[2] = a.z; lb[3] = a.w;
  }
  __syncthreads();

  float a[4] = {0.f, 0.f, 0.f, 0.f};
  const f4* P = (const f4*)(emb + (size_t)b * D_DIM * NPIX + base);

  // software pipeline, depth 4 (named buffers, static indexing)
  f4 A0 = P[tid];
  f4 A1 = P[(size_t)1 * F4_D + tid];
  f4 A2 = P[(size_t)2 * F4_D + tid];
  f4 A3 = P[(size_t)3 * F4_D + tid];

  for (int d = 0; d < D_DIM; d += 4) {
    {
      const float* td = tm[d + 0];
#pragma unroll
      for (int j = 0; j < 4; j++) { const float x = A0[j]; a[j] = fmaf(x, x - td[lb[j]], a[j]); }
      A0 = P[(size_t)((d + 4) & 31) * F4_D + tid];   // wrap: tail re-reads, L2-hot
    }
    {
      const float* td = tm[d + 1];
#pragma unroll
      for (int j = 0; j < 4; j++) { const float x = A1[j]; a[j] = fmaf(x, x - td[lb[j]], a[j]); }
      A1 = P[(size_t)((d + 5) & 31) * F4_D + tid];
    }
    {
      const float* td = tm[d + 2];
#pragma unroll
      for (int j = 0; j < 4; j++) { const float x = A2[j]; a[j] = fmaf(x, x - td[lb[j]], a[j]); }
      A2 = P[(size_t)((d + 6) & 31) * F4_D + tid];
    }
    {
      const float* td = tm[d + 3];
#pragma unroll
      for (int j = 0; j < 4; j++) { const float x = A3[j]; a[j] = fmaf(x, x - td[lb[j]], a[j]); }
      A3 = P[(size_t)((d + 7) & 31) * F4_D + tid];
    }
  }

#pragma unroll
  for (int j = 0; j < 4; j++) {
    const float d2 = a[j] + msq[lb[j]];
    const float dd = sqrtf(fmaxf(d2, 0.f));
    const float h = fmaxf(dd - 0.5f, 0.f);  // VAR_THETA
    atomicAdd(&vacc[lb[j]][col], h * h);
  }
  __syncthreads();
  if (tid < K_CL) {
    const f4* r = (const f4*)vacc[tid];
    f4 s0 = r[0], s1 = r[1], s2 = r[2], s3 = r[3];
    const float tot = (s0[0] + s0[1] + s0[2] + s0[3]) + (s1[0] + s1[1] + s1[2] + s1[3]) +
                      (s2[0] + s2[1] + s2[2] + s2[3]) + (s3[0] + s3[1] + s3[2] + s3[3]);
    unsafeAtomicAdd(&var_sums[b * K_CL + tid], tot);
  }
}

// ---------------- Final combine ----------------
__global__ __launch_bounds__(128) void k_final(const float* __restrict__ counts,
                                               const float* __restrict__ var_sums,
                                               const float* __restrict__ dist_reg,
                                               float* __restrict__ out) {
  const int t = threadIdx.x;                // t = b*16 + k
  float pc = 0.f;
  if (t < B_IMG * K_CL) pc = var_sums[t] / fmaxf(counts[t], 1.0f);
#pragma unroll
  for (int off = 8; off > 0; off >>= 1) pc += __shfl_xor(pc, off, 64);
  __shared__ float lbl[B_IMG];
  if (t < B_IMG * K_CL && (t & 15) == 0) {
    const int b = t >> 4;
    lbl[b] = pc * (1.0f / 16.0f) + dist_reg[b];
  }
  __syncthreads();
  if (t == 0) {
    float s = 0.f;
#pragma unroll
    for (int b = 0; b < B_IMG; b++) s += lbl[b];
    out[0] = s * (1.0f / B_IMG);
  }
}

extern "C" void kernel_launch(void* const* d_in, const int* in_sizes, int n_in,
                              void* d_out, int out_size, void* d_ws, size_t ws_size,
                              hipStream_t stream) {
  const float* emb = (const float*)d_in[0];
  const int* gt = (const int*)d_in[1];
  float* out = (float*)d_out;

  float* sums = (float*)d_ws;                            // 4096
  float* counts = sums + B_IMG * K_CL * D_DIM;           // 128
  float* var_sums = counts + B_IMG * K_CL;               // 128
  float* dist_reg = var_sums + B_IMG * K_CL;             // 8
  float* mt = dist_reg + B_IMG;                          // 4096 (fully written by k_means)
  float* msq_g = mt + B_IMG * D_DIM * K_CL;              // 128 (fully written by k_means)

  const size_t zero_floats = B_IMG * K_CL * D_DIM + 2 * B_IMG * K_CL + B_IMG;
  (void)hipMemsetAsync(d_ws, 0, zero_floats * sizeof(float), stream);

  k_sums<<<dim3(B_IMG * CHUNKS), dim3(256), 0, stream>>>(emb, gt, sums, counts);
  k_means<<<dim3(B_IMG), dim3(256), 0, stream>>>(sums, counts, mt, msq_g, dist_reg);
  k_var<<<dim3(B_IMG * CHUNKS), dim3(256), 0, stream>>>(emb, gt, mt, msq_g, var_sums);
  k_final<<<dim3(1), dim3(128), 0, stream>>>(counts, var_sums, dist_reg, out);
}

// Round 14
// 598.735 us; speedup vs baseline: 1.2810x; 1.2810x over previous
//
#include <hip/hip_runtime.h>

#define B_IMG 8
#define D_DIM 32
#define NPIX 262144          // 512*512
#define K_CL 16

// ---- k_sums geometry (r1 measured: 169 us) ----
#define CHUNK_S 2048
#define CHUNKS_S (NPIX / CHUNK_S)   // 128
#define PPT 8                       // pixels per thread
#define ACC_STRIDE 272              // 256 + 16

// ---- k_var geometry (r3 measured: 195 us) ----
#define CHUNK_V 1024
#define CHUNKS_V (NPIX / CHUNK_V)   // 256
#define VST 264

__device__ __forceinline__ float wave_sum(float v) {
#pragma unroll
  for (int off = 32; off > 0; off >>= 1) v += __shfl_xor(v, off, 64);
  return v;
}

// r1 flush: 4 waves x 4 rows, b128 read + zero + 6-shuffle reduce + atomic.
__device__ __forceinline__ void flush_acc(float (*acc)[ACC_STRIDE], int tid,
                                          float* target, int stride) {
  const int w = tid >> 6, lane = tid & 63;
#pragma unroll
  for (int rr = 0; rr < 4; rr++) {
    const int r = (w << 2) | rr;
    float4 v = *(float4*)(&acc[r][lane << 2]);
    *(float4*)(&acc[r][lane << 2]) = make_float4(0.f, 0.f, 0.f, 0.f);
    float tot = wave_sum(v.x + v.y + v.z + v.w);
    if (lane == 0) unsafeAtomicAdd(&target[r * stride], tot);
  }
}

// ---------------- Pass A: counts + per-(k,d) sums (r1 structure) ----------------
__global__ __launch_bounds__(256) void k_sums(const float* __restrict__ emb,
                                              const int* __restrict__ gt,
                                              float* __restrict__ sums,
                                              float* __restrict__ counts) {
  __shared__ alignas(16) float acc[K_CL][ACC_STRIDE];
  const int tid = threadIdx.x;
  const int b = blockIdx.x >> 7;            // CHUNKS_S == 128
  const int chunk = blockIdx.x & (CHUNKS_S - 1);
  const int base = chunk * CHUNK_S;

  int lb[PPT];
  {
    const int4* lp = (const int4*)(gt + (size_t)b * NPIX + base);
    int4 a0 = lp[tid];
    int4 a1 = lp[256 + tid];
    lb[0] = a0.x; lb[1] = a0.y; lb[2] = a0.z; lb[3] = a0.w;
    lb[4] = a1.x; lb[5] = a1.y; lb[6] = a1.z; lb[7] = a1.w;
  }
#pragma unroll
  for (int k = 0; k < K_CL; k++) acc[k][tid] = 0.f;
  __syncthreads();

#pragma unroll
  for (int j = 0; j < PPT; j++) acc[lb[j]][tid] += 1.0f;
  __syncthreads();
  flush_acc(acc, tid, counts + b * K_CL, 1);
  __syncthreads();

  for (int d = 0; d < D_DIM; d++) {
    const float4* pp = (const float4*)(emb + ((size_t)b * D_DIM + d) * NPIX + base);
    alignas(16) float v[PPT];
    *(float4*)&v[0] = pp[tid];
    *(float4*)&v[4] = pp[256 + tid];
#pragma unroll
    for (int j = 0; j < PPT; j++) acc[lb[j]][tid] += v[j];
    __syncthreads();
    flush_acc(acc, tid, sums + (size_t)b * K_CL * D_DIM + d, D_DIM);
    __syncthreads();
  }
}

// ------------- Pass C: variance + distance/reg (r3 structure) -------------
__global__ __launch_bounds__(256) void k_var(const float* __restrict__ emb,
                                             const int* __restrict__ gt,
                                             const float* __restrict__ sums,
                                             const float* __restrict__ counts,
                                             float* __restrict__ var_sums,
                                             float* __restrict__ dist_reg) {
  __shared__ float acc[K_CL][VST];
  __shared__ float4 mk4[K_CL][9];        // means, transposed + padded
  __shared__ float msq[K_CL];
  __shared__ float red4[4];
  const int tid = threadIdx.x;
  const int b = blockIdx.x >> 8;         // CHUNKS_V == 256
  const int chunk = blockIdx.x & (CHUNKS_V - 1);
  const int base = chunk * CHUNK_V;

  float* mkf = (float*)mk4;              // row stride 36 floats
#pragma unroll
  for (int e0 = 0; e0 < 2; e0++) {
    const int e = tid + (e0 << 8);       // e = k*32 + d
    const int k = e >> 5, d = e & 31;
    const float c = fmaxf(counts[b * K_CL + k], 1.0f);
    mkf[k * 36 + d] = sums[(size_t)b * K_CL * D_DIM + e] / c;
  }
#pragma unroll
  for (int k = 0; k < K_CL; k++) acc[k][tid] = 0.f;
  __syncthreads();
  if (tid < K_CL) {
    float s = 0.f;
#pragma unroll
    for (int g = 0; g < 8; g++) {
      float4 m = mk4[tid][g];
      s = fmaf(m.x, m.x, s); s = fmaf(m.y, m.y, s);
      s = fmaf(m.z, m.z, s); s = fmaf(m.w, m.w, s);
    }
    msq[tid] = s;
  }
  __syncthreads();

  if (chunk == 0) {
    const int i = tid >> 4, j = tid & 15;
    float sq = 0.f;
#pragma unroll
    for (int g = 0; g < 8; g++) {
      float4 mi = mk4[i][g], mj = mk4[j][g];
      float dx = mi.x - mj.x, dy = mi.y - mj.y, dz = mi.z - mj.z, dw = mi.w - mj.w;
      sq = fmaf(dx, dx, sq); sq = fmaf(dy, dy, sq);
      sq = fmaf(dz, dz, sq); sq = fmaf(dw, dw, sq);
    }
    float contrib = 0.f;
    if (i < j) {
      const float h = fmaxf(3.0f - sqrtf(sq), 0.0f);   // 2*DIST_THETA
      contrib = h * h;
    }
    const float tot = wave_sum(contrib);
    if ((tid & 63) == 0) red4[tid >> 6] = tot;
    __syncthreads();
    if (tid == 0) {
      const float dist = (red4[0] + red4[1] + red4[2] + red4[3]) * (1.0f / 240.0f);
      float reg = 0.f;
#pragma unroll
      for (int k = 0; k < K_CL; k++) reg += sqrtf(msq[k]);
      dist_reg[b] = dist + 0.001f * (reg * (1.0f / 16.0f));
    }
  }

  int lb[4];
  {
    const int4 a = ((const int4*)(gt + (size_t)b * NPIX + base))[tid];
    lb[0] = a.x; lb[1] = a.y; lb[2] = a.z; lb[3] = a.w;
  }
  float a[4] = {0.f, 0.f, 0.f, 0.f};

#pragma unroll 2
  for (int g = 0; g < 8; g++) {
    const float* eb = emb + ((size_t)b * D_DIM + g * 4) * NPIX + base;
    float4 v[4];
#pragma unroll
    for (int d = 0; d < 4; d++)
      v[d] = ((const float4*)(eb + (size_t)d * NPIX))[tid];
#pragma unroll
    for (int j = 0; j < 4; j++) {
      const float4 m4 = mk4[lb[j]][g];
#pragma unroll
      for (int d = 0; d < 4; d++) {
        const float x = ((const float*)&v[d])[j];
        const float mm = ((const float*)&m4)[d];
        a[j] = fmaf(x, x - 2.0f * mm, a[j]);
      }
    }
  }
#pragma unroll
  for (int j = 0; j < 4; j++) {
    const float d2 = a[j] + msq[lb[j]];
    const float dd = sqrtf(fmaxf(d2, 0.f));
    const float h = fmaxf(dd - 0.5f, 0.f);             // VAR_THETA
    acc[lb[j]][tid] += h * h;
  }
  __syncthreads();

  const int w = tid >> 6, lane = tid & 63;
#pragma unroll
  for (int rr = 0; rr < 4; rr++) {
    const int r = (w << 2) | rr;
    float4 vv = *(float4*)(&acc[r][lane << 2]);
    float tot = wave_sum(vv.x + vv.y + vv.z + vv.w);
    if (lane == 0) unsafeAtomicAdd(&var_sums[b * K_CL + r], tot);
  }
}

// ---------------- Final combine ----------------
__global__ __launch_bounds__(128) void k_final(const float* __restrict__ counts,
                                               const float* __restrict__ var_sums,
                                               const float* __restrict__ dist_reg,
                                               float* __restrict__ out) {
  const int t = threadIdx.x;             // t = b*16 + k
  float pc = 0.f;
  if (t < B_IMG * K_CL) pc = var_sums[t] / fmaxf(counts[t], 1.0f);
#pragma unroll
  for (int off = 8; off > 0; off >>= 1) pc += __shfl_xor(pc, off, 64);
  __shared__ float lbl[B_IMG];
  if (t < B_IMG * K_CL && (t & 15) == 0) {
    const int b = t >> 4;
    lbl[b] = pc * (1.0f / 16.0f) + dist_reg[b];
  }
  __syncthreads();
  if (t == 0) {
    float s = 0.f;
#pragma unroll
    for (int b = 0; b < B_IMG; b++) s += lbl[b];
    out[0] = s * (1.0f / B_IMG);
  }
}

extern "C" void kernel_launch(void* const* d_in, const int* in_sizes, int n_in,
                              void* d_out, int out_size, void* d_ws, size_t ws_size,
                              hipStream_t stream) {
  const float* emb = (const float*)d_in[0];
  const int* gt = (const int*)d_in[1];
  float* out = (float*)d_out;

  float* sums = (float*)d_ws;                           // 4096 floats
  float* counts = sums + B_IMG * K_CL * D_DIM;          // 128
  float* var_sums = counts + B_IMG * K_CL;              // 128
  float* dist_reg = var_sums + B_IMG * K_CL;            // 8

  const size_t ws_floats = B_IMG * K_CL * D_DIM + 2 * B_IMG * K_CL + B_IMG;
  (void)hipMemsetAsync(d_ws, 0, ws_floats * sizeof(float), stream);

  k_sums<<<dim3(B_IMG * CHUNKS_S), dim3(256), 0, stream>>>(emb, gt, sums, counts);
  k_var<<<dim3(B_IMG * CHUNKS_V), dim3(256), 0, stream>>>(emb, gt, sums, counts,
                                                          var_sums, dist_reg);
  k_final<<<dim3(1), dim3(128), 0, stream>>>(counts, var_sums, dist_reg, out);
}